// Round 4
// baseline (83.232 us; speedup 1.0000x reference)
//
#include <hip/hip_runtime.h>

#define ROWS   681408        // 64 * 10647
#define NBINS  8192
#define CAP    64            // bucket capacity per bin
#define TOPK   192
#define SELCAP 256

#define RPB    16            // rows per block (decode)
#define F4PB   340           // float4 per block = RPB*85/4

// ws word offsets
#define WS_ROW0     4        // 6 floats: score, class, x1,y1,x2,y2
#define WS_CNT      16       // 8192 uints -> words 16..8207 (16B aligned)
#define WS_BUCKET   8448     // uint2[NBINS*CAP] -> 1,048,576 words (4 MB)

__device__ __forceinline__ float clip01(float v) {
    return fminf(fmaxf(v, 0.0f), 1.0f);
}

__global__ void init_kernel(unsigned int* __restrict__ ws) {
    int i = blockIdx.x * 256 + threadIdx.x;
    if (i < NBINS) ws[WS_CNT + i] = 0u;
}

__global__ __launch_bounds__(256) void decode_kernel(
    const float4* __restrict__ y4, unsigned int* __restrict__ ws)
{
    __shared__ float lds[RPB * 85];

    const int t = threadIdx.x;
    const int blk = blockIdx.x;

    // ---- stage 16 rows (5440 B) via fully-coalesced float4 loads
    {
        const float4* src = y4 + (size_t)blk * F4PB;
        float4* dst = (float4*)lds;
        #pragma unroll
        for (int i = t; i < F4PB; i += 256) dst[i] = src[i];
    }
    __syncthreads();

    const int lane = t & 63;
    const int rl   = t >> 4;      // local row 0..15 (= wave*4 + group)
    const int s    = lane & 15;
    const int row  = blk * RPB + rl;

    const float* p = lds + rl * 85;
    float e0 = p[s];
    float e1 = p[s + 16];
    float e2 = p[s + 32];
    float e3 = p[s + 48];
    float e4 = p[s + 64];
    float e5 = (s < 5) ? p[s + 80] : -1.0f;

    // per-lane argmax over probs (elements 5..84), fold in ascending class
    // order with strict > so the FIRST index wins ties (jnp.argmax semantics)
    float bv; int bc;
    if (s >= 5) { bv = e0; bc = s - 5; } else { bv = -1.0f; bc = 1 << 20; }
    if (e1 > bv) { bv = e1; bc = s + 11; }
    if (e2 > bv) { bv = e2; bc = s + 27; }
    if (e3 > bv) { bv = e3; bc = s + 43; }
    if (e4 > bv) { bv = e4; bc = s + 59; }
    if (s < 5 && e5 > bv) { bv = e5; bc = s + 75; }

    #pragma unroll
    for (int m = 8; m >= 1; m >>= 1) {
        float ov = __shfl_xor(bv, m, 64);
        int   oc = __shfl_xor(bc, m, 64);
        if (ov > bv || (ov == bv && oc < bc)) { bv = ov; bc = oc; }
    }

    if (s == 0) {
        float bx = p[0], by = p[1], bw = p[2], bh = p[3], cf = p[4];
        float score = cf * bv;
        float x  = clip01(bx / 416.0f);
        float yy = clip01(by / 416.0f);
        float w  = clip01(bw / 416.0f);
        float h  = clip01(bh / 416.0f);
        float x1 = clip01(x  - w * 0.5f);
        float y1 = clip01(yy - h * 0.5f);
        float x2 = clip01(x  + w * 0.5f);
        float y2 = clip01(yy + h * 0.5f);
        bool keep = (((x2 - x1) * (y2 - y1)) > 0.0005f) && (score > 0.5f);
        if (keep) {
            int bin = (int)((score - 0.5f) * (2.0f * (float)NBINS));
            bin = min(max(bin, 0), NBINS - 1);
            unsigned int pos = atomicAdd(&ws[WS_CNT + bin], 1u);
            if (pos < (unsigned int)CAP) {
                uint2* bucket = (uint2*)&ws[WS_BUCKET];
                bucket[bin * CAP + pos] =
                    make_uint2(__float_as_uint(score), (unsigned int)row);
            }
        }
        if (row == 0) {
            float* r0 = (float*)&ws[WS_ROW0];
            r0[0] = score; r0[1] = (float)bc;
            r0[2] = x1; r0[3] = y1; r0[4] = x2; r0[5] = y2;
        }
    }
}

__global__ __launch_bounds__(256) void nms_kernel(
    const float* __restrict__ y, unsigned int* __restrict__ ws,
    float* __restrict__ out)
{
    __shared__ unsigned int chunk[256];
    __shared__ unsigned long long keys[SELCAP];
    __shared__ float4 sboxes[SELCAP];
    __shared__ int s_bstar;
    __shared__ unsigned int s_m;
    __shared__ int s_picks;
    __shared__ unsigned int s_idx[10];
    __shared__ float s_score[10];
    __shared__ float4 s_box[10];
    __shared__ int s_cls[10];

    const int t = threadIdx.x;
    const uint2* bucket = (const uint2*)&ws[WS_BUCKET];

    // ---- threshold: find bin b* so that count(bins >= b*) >= min(TOPK, total)
    unsigned int ssum = 0;
    {
        const uint4* cnt4 = (const uint4*)&ws[WS_CNT];
        #pragma unroll
        for (int i = 0; i < 8; i++) {
            uint4 v = cnt4[t * 8 + i];
            ssum += min(v.x, (unsigned int)CAP) + min(v.y, (unsigned int)CAP)
                  + min(v.z, (unsigned int)CAP) + min(v.w, (unsigned int)CAP);
        }
    }
    chunk[t] = ssum;
    // pre-zero sort keys while we're here
    for (int i = t; i < SELCAP; i += 256) keys[i] = 0ull;
    __syncthreads();
    if (t == 0) {
        unsigned int total = 0;
        for (int c = 0; c < 256; c++) total += chunk[c];
        unsigned int target = (total < (unsigned int)TOPK) ? total : (unsigned int)TOPK;
        int b = NBINS;   // select nothing if no candidates
        if (target > 0) {
            unsigned int cum = 0;
            int c;
            for (c = 255; c >= 0; c--) {
                if (cum + chunk[c] >= target) break;
                cum += chunk[c];
            }
            if (c < 0) {
                b = 0;
            } else {
                int bb;
                for (bb = c * 32 + 31; bb >= c * 32; bb--) {
                    unsigned int cc = ws[WS_CNT + bb];
                    cum += (cc < (unsigned int)CAP) ? cc : (unsigned int)CAP;
                    if (cum >= target) break;
                }
                b = max(bb, c * 32);
            }
        }
        s_bstar = b;
        s_m = 0u;
    }
    __syncthreads();

    // ---- gather all entries from bins >= b* (order fixed by the sort below)
    for (int bin = s_bstar + t; bin < NBINS; bin += 256) {
        unsigned int c = ws[WS_CNT + bin];
        if (c > (unsigned int)CAP) c = CAP;
        for (unsigned int j = 0; j < c; j++) {
            uint2 cv = bucket[bin * CAP + j];
            unsigned int pos = atomicAdd(&s_m, 1u);
            if (pos < (unsigned int)SELCAP)
                keys[pos] = ((unsigned long long)cv.x << 32) |
                            (unsigned long long)(0xFFFFFFFFu - cv.y);
        }
    }
    __syncthreads();
    unsigned int M = s_m;
    if (M > (unsigned int)SELCAP) M = SELCAP;

    // ---- bitonic sort, descending: (score desc, idx asc)
    for (int k = 2; k <= SELCAP; k <<= 1) {
        for (int j = k >> 1; j > 0; j >>= 1) {
            for (int i = t; i < SELCAP; i += 256) {
                int ixj = i ^ j;
                if (ixj > i) {
                    unsigned long long a = keys[i], b = keys[ixj];
                    bool descSeg = ((i & k) == 0);
                    if (descSeg ? (a < b) : (a > b)) { keys[i] = b; keys[ixj] = a; }
                }
            }
            __syncthreads();
        }
    }

    // ---- decode boxes for the sorted prefix
    for (int i = t; i < (int)M; i += 256) {
        unsigned int idx = 0xFFFFFFFFu - (unsigned int)(keys[i] & 0xFFFFFFFFull);
        const float* p = y + (size_t)idx * 85;
        float x  = clip01(p[0] / 416.0f);
        float yy = clip01(p[1] / 416.0f);
        float w  = clip01(p[2] / 416.0f);
        float h  = clip01(p[3] / 416.0f);
        sboxes[i] = make_float4(clip01(x - w * 0.5f), clip01(yy - h * 0.5f),
                                clip01(x + w * 0.5f), clip01(yy + h * 0.5f));
    }
    __syncthreads();

    // ---- sequential greedy-NMS scan (exact equivalent of the 10-step argmax loop)
    if (t == 0) {
        int np = 0;
        for (int i = 0; i < (int)M && np < 10; i++) {
            float4 b = sboxes[i];
            bool ok = true;
            for (int kk = 0; kk < np; kk++) {
                float4 r = s_box[kk];
                float ix1 = fmaxf(r.x, b.x);
                float iy1 = fmaxf(r.y, b.y);
                float ix2 = fminf(r.z, b.z);
                float iy2 = fminf(r.w, b.w);
                float inter = fmaxf(ix2 - ix1, 0.0f) * fmaxf(iy2 - iy1, 0.0f);
                float aref = (r.z - r.x) * (r.w - r.y);
                float aall = (b.z - b.x) * (b.w - b.y);
                float iou = inter / (aref + aall - inter + 1e-10f);
                if (iou > 0.45f) { ok = false; break; }
            }
            if (ok) {
                s_box[np] = b;
                s_idx[np] = 0xFFFFFFFFu - (unsigned int)(keys[i] & 0xFFFFFFFFull);
                s_score[np] = __uint_as_float((unsigned int)(keys[i] >> 32));
                np++;
            }
        }
        s_picks = np;
    }
    __syncthreads();

    // ---- class (argmax of 80 probs) for each pick: 16 lanes per pick
    {
        int p = t >> 4, s = t & 15;
        float bv = -1.0f; int bc = 1 << 20;
        if (p < s_picks) {
            const float* pr = y + (size_t)s_idx[p] * 85 + 5;
            #pragma unroll
            for (int kk = 0; kk < 5; kk++) {
                float v = pr[s + 16 * kk];
                int c = s + 16 * kk;
                if (v > bv) { bv = v; bc = c; }
            }
        }
        #pragma unroll
        for (int m = 8; m >= 1; m >>= 1) {
            float ov = __shfl_xor(bv, m, 64);
            int   oc = __shfl_xor(bc, m, 64);
            if (ov > bv || (ov == bv && oc < bc)) { bv = ov; bc = oc; }
        }
        if (p < s_picks && s == 0) s_cls[p] = bc;
    }
    __syncthreads();

    if (t == 0) {
        const float* r0 = (const float*)&ws[WS_ROW0];
        float score0 = r0[0], class0 = r0[1];
        float4 box0 = make_float4(r0[2], r0[3], r0[4], r0[5]);
        for (int kk = 0; kk < 10; kk++) {
            bool v = kk < s_picks;
            float4 b = v ? s_box[kk] : box0;
            out[4 * kk + 0] = b.x;
            out[4 * kk + 1] = b.y;
            out[4 * kk + 2] = b.z;
            out[4 * kk + 3] = b.w;
            out[40 + kk] = v ? s_score[kk] : score0;
            out[50 + kk] = v ? (float)s_cls[kk] : class0;
            out[60 + kk] = v ? 1.0f : 0.0f;
        }
    }
}

extern "C" void kernel_launch(void* const* d_in, const int* in_sizes, int n_in,
                              void* d_out, int out_size, void* d_ws, size_t ws_size,
                              hipStream_t stream)
{
    const float* y = (const float*)d_in[0];
    unsigned int* ws = (unsigned int*)d_ws;

    init_kernel<<<dim3(NBINS / 256), dim3(256), 0, stream>>>(ws);
    decode_kernel<<<dim3(ROWS / RPB), dim3(256), 0, stream>>>((const float4*)y, ws);
    nms_kernel<<<dim3(1), dim3(256), 0, stream>>>(y, ws, (float*)d_out);
}

// Round 5
// 81.115 us; speedup vs baseline: 1.0261x; 1.0261x over previous
//
#include <hip/hip_runtime.h>

#define ROWS   681408        // 64 * 10647
#define NBINS  8192
#define CAP    64            // bucket capacity per bin
#define TOPK   192
#define SELCAP 256

// ws word offsets
#define WS_ROW0     4        // 6 floats: score, class, x1,y1,x2,y2
#define WS_CNT      16       // 8192 uints -> words 16..8207 (16B aligned)
#define WS_BUCKET   8448     // uint2[NBINS*CAP] -> 1,048,576 words (4 MB)

__device__ __forceinline__ float clip01(float v) {
    return fminf(fmaxf(v, 0.0f), 1.0f);
}

__global__ void init_kernel(unsigned int* __restrict__ ws) {
    int i = blockIdx.x * 256 + threadIdx.x;
    if (i < NBINS) ws[WS_CNT + i] = 0u;
}

__global__ __launch_bounds__(256) void decode_kernel(
    const float* __restrict__ y, unsigned int* __restrict__ ws)
{
    const int t    = threadIdx.x;
    const int lane = t & 63;
    const int wave = t >> 6;
    const int g    = lane >> 4;   // 16-lane group within wave
    const int s    = lane & 15;
    const int row  = blockIdx.x * 16 + wave * 4 + g;   // exact grid, no tail

    const float* p = y + (size_t)row * 85;

    // ---- prefix: elements 0..7 only (box, conf, probs 0..2) = 32 B/group
    float e0 = (s < 8) ? p[s] : -1.0f;

    const int gb = lane & 48;   // group base lane
    float cf = __shfl(e0, gb + 4, 64);

    // conservative gate: score = conf * max(probs) <= conf, so conf <= 0.5
    // can never pass score > 0.5. Row 0 always decoded (fallback output).
    bool gate = (cf > 0.5f) || (row == 0);
    if (!gate) return;          // uniform per 16-lane group

    // ---- full row load for surviving groups
    if (s >= 8) e0 = p[s];
    float e1 = p[s + 16];
    float e2 = p[s + 32];
    float e3 = p[s + 48];
    float e4 = p[s + 64];
    float e5 = (s < 5) ? p[s + 80] : -1.0f;

    // per-lane argmax over probs (elements 5..84), fold in ascending class
    // order with strict > so the FIRST index wins ties (jnp.argmax semantics)
    float bv; int bc;
    if (s >= 5) { bv = e0; bc = s - 5; } else { bv = -1.0f; bc = 1 << 20; }
    if (e1 > bv) { bv = e1; bc = s + 11; }
    if (e2 > bv) { bv = e2; bc = s + 27; }
    if (e3 > bv) { bv = e3; bc = s + 43; }
    if (e4 > bv) { bv = e4; bc = s + 59; }
    if (s < 5 && e5 > bv) { bv = e5; bc = s + 75; }

    #pragma unroll
    for (int m = 8; m >= 1; m >>= 1) {
        float ov = __shfl_xor(bv, m, 64);
        int   oc = __shfl_xor(bc, m, 64);
        if (ov > bv || (ov == bv && oc < bc)) { bv = ov; bc = oc; }
    }

    float bx = __shfl(e0, gb + 0, 64);
    float by = __shfl(e0, gb + 1, 64);
    float bw = __shfl(e0, gb + 2, 64);
    float bh = __shfl(e0, gb + 3, 64);

    if (s == 0) {
        float score = cf * bv;
        float x  = clip01(bx / 416.0f);
        float yy = clip01(by / 416.0f);
        float w  = clip01(bw / 416.0f);
        float h  = clip01(bh / 416.0f);
        float x1 = clip01(x  - w * 0.5f);
        float y1 = clip01(yy - h * 0.5f);
        float x2 = clip01(x  + w * 0.5f);
        float y2 = clip01(yy + h * 0.5f);
        bool keep = (((x2 - x1) * (y2 - y1)) > 0.0005f) && (score > 0.5f);
        if (keep) {
            int bin = (int)((score - 0.5f) * (2.0f * (float)NBINS));
            bin = min(max(bin, 0), NBINS - 1);
            unsigned int pos = atomicAdd(&ws[WS_CNT + bin], 1u);
            if (pos < (unsigned int)CAP) {
                uint2* bucket = (uint2*)&ws[WS_BUCKET];
                bucket[bin * CAP + pos] =
                    make_uint2(__float_as_uint(score), (unsigned int)row);
            }
        }
        if (row == 0) {
            float* r0 = (float*)&ws[WS_ROW0];
            r0[0] = score; r0[1] = (float)bc;
            r0[2] = x1; r0[3] = y1; r0[4] = x2; r0[5] = y2;
        }
    }
}

__global__ __launch_bounds__(256) void nms_kernel(
    const float* __restrict__ y, unsigned int* __restrict__ ws,
    float* __restrict__ out)
{
    __shared__ unsigned int chunk[256];
    __shared__ unsigned long long keys[SELCAP];
    __shared__ float4 sboxes[SELCAP];
    __shared__ int s_bstar;
    __shared__ unsigned int s_m;
    __shared__ int s_picks;
    __shared__ unsigned int s_idx[10];
    __shared__ float s_score[10];
    __shared__ float4 s_box[10];
    __shared__ int s_cls[10];

    const int t = threadIdx.x;
    const uint2* bucket = (const uint2*)&ws[WS_BUCKET];

    // ---- threshold: find bin b* so that count(bins >= b*) >= min(TOPK, total)
    unsigned int ssum = 0;
    {
        const uint4* cnt4 = (const uint4*)&ws[WS_CNT];
        #pragma unroll
        for (int i = 0; i < 8; i++) {
            uint4 v = cnt4[t * 8 + i];
            ssum += min(v.x, (unsigned int)CAP) + min(v.y, (unsigned int)CAP)
                  + min(v.z, (unsigned int)CAP) + min(v.w, (unsigned int)CAP);
        }
    }
    chunk[t] = ssum;
    // pre-zero sort keys while we're here
    for (int i = t; i < SELCAP; i += 256) keys[i] = 0ull;
    __syncthreads();
    if (t == 0) {
        unsigned int total = 0;
        for (int c = 0; c < 256; c++) total += chunk[c];
        unsigned int target = (total < (unsigned int)TOPK) ? total : (unsigned int)TOPK;
        int b = NBINS;   // select nothing if no candidates
        if (target > 0) {
            unsigned int cum = 0;
            int c;
            for (c = 255; c >= 0; c--) {
                if (cum + chunk[c] >= target) break;
                cum += chunk[c];
            }
            if (c < 0) {
                b = 0;
            } else {
                int bb;
                for (bb = c * 32 + 31; bb >= c * 32; bb--) {
                    unsigned int cc = ws[WS_CNT + bb];
                    cum += (cc < (unsigned int)CAP) ? cc : (unsigned int)CAP;
                    if (cum >= target) break;
                }
                b = max(bb, c * 32);
            }
        }
        s_bstar = b;
        s_m = 0u;
    }
    __syncthreads();

    // ---- gather all entries from bins >= b* (order fixed by the sort below)
    for (int bin = s_bstar + t; bin < NBINS; bin += 256) {
        unsigned int c = ws[WS_CNT + bin];
        if (c > (unsigned int)CAP) c = CAP;
        for (unsigned int j = 0; j < c; j++) {
            uint2 cv = bucket[bin * CAP + j];
            unsigned int pos = atomicAdd(&s_m, 1u);
            if (pos < (unsigned int)SELCAP)
                keys[pos] = ((unsigned long long)cv.x << 32) |
                            (unsigned long long)(0xFFFFFFFFu - cv.y);
        }
    }
    __syncthreads();
    unsigned int M = s_m;
    if (M > (unsigned int)SELCAP) M = SELCAP;

    // ---- bitonic sort, descending: (score desc, idx asc)
    for (int k = 2; k <= SELCAP; k <<= 1) {
        for (int j = k >> 1; j > 0; j >>= 1) {
            for (int i = t; i < SELCAP; i += 256) {
                int ixj = i ^ j;
                if (ixj > i) {
                    unsigned long long a = keys[i], b = keys[ixj];
                    bool descSeg = ((i & k) == 0);
                    if (descSeg ? (a < b) : (a > b)) { keys[i] = b; keys[ixj] = a; }
                }
            }
            __syncthreads();
        }
    }

    // ---- decode boxes for the sorted prefix
    for (int i = t; i < (int)M; i += 256) {
        unsigned int idx = 0xFFFFFFFFu - (unsigned int)(keys[i] & 0xFFFFFFFFull);
        const float* p = y + (size_t)idx * 85;
        float x  = clip01(p[0] / 416.0f);
        float yy = clip01(p[1] / 416.0f);
        float w  = clip01(p[2] / 416.0f);
        float h  = clip01(p[3] / 416.0f);
        sboxes[i] = make_float4(clip01(x - w * 0.5f), clip01(yy - h * 0.5f),
                                clip01(x + w * 0.5f), clip01(yy + h * 0.5f));
    }
    __syncthreads();

    // ---- sequential greedy-NMS scan (exact equivalent of the 10-step argmax loop)
    if (t == 0) {
        int np = 0;
        for (int i = 0; i < (int)M && np < 10; i++) {
            float4 b = sboxes[i];
            bool ok = true;
            for (int kk = 0; kk < np; kk++) {
                float4 r = s_box[kk];
                float ix1 = fmaxf(r.x, b.x);
                float iy1 = fmaxf(r.y, b.y);
                float ix2 = fminf(r.z, b.z);
                float iy2 = fminf(r.w, b.w);
                float inter = fmaxf(ix2 - ix1, 0.0f) * fmaxf(iy2 - iy1, 0.0f);
                float aref = (r.z - r.x) * (r.w - r.y);
                float aall = (b.z - b.x) * (b.w - b.y);
                float iou = inter / (aref + aall - inter + 1e-10f);
                if (iou > 0.45f) { ok = false; break; }
            }
            if (ok) {
                s_box[np] = b;
                s_idx[np] = 0xFFFFFFFFu - (unsigned int)(keys[i] & 0xFFFFFFFFull);
                s_score[np] = __uint_as_float((unsigned int)(keys[i] >> 32));
                np++;
            }
        }
        s_picks = np;
    }
    __syncthreads();

    // ---- class (argmax of 80 probs) for each pick: 16 lanes per pick
    {
        int p = t >> 4, s = t & 15;
        float bv = -1.0f; int bc = 1 << 20;
        if (p < s_picks) {
            const float* pr = y + (size_t)s_idx[p] * 85 + 5;
            #pragma unroll
            for (int kk = 0; kk < 5; kk++) {
                float v = pr[s + 16 * kk];
                int c = s + 16 * kk;
                if (v > bv) { bv = v; bc = c; }
            }
        }
        #pragma unroll
        for (int m = 8; m >= 1; m >>= 1) {
            float ov = __shfl_xor(bv, m, 64);
            int   oc = __shfl_xor(bc, m, 64);
            if (ov > bv || (ov == bv && oc < bc)) { bv = ov; bc = oc; }
        }
        if (p < s_picks && s == 0) s_cls[p] = bc;
    }
    __syncthreads();

    if (t == 0) {
        const float* r0 = (const float*)&ws[WS_ROW0];
        float score0 = r0[0], class0 = r0[1];
        float4 box0 = make_float4(r0[2], r0[3], r0[4], r0[5]);
        for (int kk = 0; kk < 10; kk++) {
            bool v = kk < s_picks;
            float4 b = v ? s_box[kk] : box0;
            out[4 * kk + 0] = b.x;
            out[4 * kk + 1] = b.y;
            out[4 * kk + 2] = b.z;
            out[4 * kk + 3] = b.w;
            out[40 + kk] = v ? s_score[kk] : score0;
            out[50 + kk] = v ? (float)s_cls[kk] : class0;
            out[60 + kk] = v ? 1.0f : 0.0f;
        }
    }
}

extern "C" void kernel_launch(void* const* d_in, const int* in_sizes, int n_in,
                              void* d_out, int out_size, void* d_ws, size_t ws_size,
                              hipStream_t stream)
{
    const float* y = (const float*)d_in[0];
    unsigned int* ws = (unsigned int*)d_ws;

    init_kernel<<<dim3(NBINS / 256), dim3(256), 0, stream>>>(ws);
    decode_kernel<<<dim3(ROWS / 16), dim3(256), 0, stream>>>(y, ws);
    nms_kernel<<<dim3(1), dim3(256), 0, stream>>>(y, ws, (float*)d_out);
}

// Round 6
// 78.087 us; speedup vs baseline: 1.0659x; 1.0388x over previous
//
#include <hip/hip_runtime.h>

#define ROWS   681408        // 64 * 10647
#define NBINS  8192
#define CAP    64            // bucket capacity per bin
#define TOPK   192
#define SELCAP 256

// ws word offsets
#define WS_ROW0     4        // 6 floats: score, class, x1,y1,x2,y2
#define WS_CNT      16       // 8192 uints -> words 16..8207 (16B aligned)
#define WS_BUCKET   8448     // uint2[NBINS*CAP] -> 1,048,576 words (4 MB)

__device__ __forceinline__ float clip01(float v) {
    return fminf(fmaxf(v, 0.0f), 1.0f);
}

__global__ void init_kernel(unsigned int* __restrict__ ws) {
    int i = blockIdx.x * 256 + threadIdx.x;
    if (i < NBINS) ws[WS_CNT + i] = 0u;
}

__global__ __launch_bounds__(256) void decode_kernel(
    const float* __restrict__ y, unsigned int* __restrict__ ws)
{
    const int t    = threadIdx.x;
    const int lane = t & 63;
    const int wave = t >> 6;
    const int g    = lane >> 4;   // 16-lane group within wave
    const int s    = lane & 15;
    const int row  = blockIdx.x * 16 + wave * 4 + g;   // exact grid, no tail

    const float*  p  = y + (size_t)row * 85;
    const float2* p2 = (const float2*)p;   // row base = 1360*row bytes, 8B-aligned

    // 3 wide loads per lane instead of 6 scalars; lane s owns elems
    // {2s,2s+1}, {2s+32,2s+33}, {2s+64,2s+65}
    float2 A = p2[s];
    float2 B = p2[s + 16];
    float c0 = -1.0f, c1 = -1.0f;
    if (s < 10) { float2 C = p2[s + 32]; c0 = C.x; c1 = C.y; }
    else if (s == 10) { c0 = p[84]; }   // avoid 4B OOB on last row

    // per-lane argmax over probs (elements 5..84), folding owned elements in
    // increasing order with strict > (first-index-wins = jnp.argmax), then
    // cross-lane reduce with min-class tie-break. Classes partition lanes.
    float bv = -1.0f; int bc = 1 << 20;
    {
        int e = 2 * s;
        if (e >= 5 && A.x > bv) { bv = A.x; bc = e - 5; }
        if (e + 1 >= 5 && A.y > bv) { bv = A.y; bc = e - 4; }
        if (B.x > bv) { bv = B.x; bc = e + 27; }          // e+32 >= 32 >= 5
        if (B.y > bv) { bv = B.y; bc = e + 28; }
        if (e + 64 <= 84 && c0 > bv) { bv = c0; bc = e + 59; }
        if (e + 65 <= 84 && c1 > bv) { bv = c1; bc = e + 60; }
    }

    #pragma unroll
    for (int m = 8; m >= 1; m >>= 1) {
        float ov = __shfl_xor(bv, m, 64);
        int   oc = __shfl_xor(bc, m, 64);
        if (ov > bv || (ov == bv && oc < bc)) { bv = ov; bc = oc; }
    }

    const int gb = lane & 48;   // group base lane
    float bx = __shfl(A.x, gb + 0, 64);
    float by = __shfl(A.y, gb + 0, 64);
    float bw = __shfl(A.x, gb + 1, 64);
    float bh = __shfl(A.y, gb + 1, 64);
    float cf = __shfl(A.x, gb + 2, 64);

    if (s == 0) {
        float score = cf * bv;
        float x  = clip01(bx / 416.0f);
        float yy = clip01(by / 416.0f);
        float w  = clip01(bw / 416.0f);
        float h  = clip01(bh / 416.0f);
        float x1 = clip01(x  - w * 0.5f);
        float y1 = clip01(yy - h * 0.5f);
        float x2 = clip01(x  + w * 0.5f);
        float y2 = clip01(yy + h * 0.5f);
        bool keep = (((x2 - x1) * (y2 - y1)) > 0.0005f) && (score > 0.5f);
        if (keep) {
            int bin = (int)((score - 0.5f) * (2.0f * (float)NBINS));
            bin = min(max(bin, 0), NBINS - 1);
            unsigned int pos = atomicAdd(&ws[WS_CNT + bin], 1u);
            if (pos < (unsigned int)CAP) {
                uint2* bucket = (uint2*)&ws[WS_BUCKET];
                bucket[bin * CAP + pos] =
                    make_uint2(__float_as_uint(score), (unsigned int)row);
            }
        }
        if (row == 0) {
            float* r0 = (float*)&ws[WS_ROW0];
            r0[0] = score; r0[1] = (float)bc;
            r0[2] = x1; r0[3] = y1; r0[4] = x2; r0[5] = y2;
        }
    }
}

__global__ __launch_bounds__(256) void nms_kernel(
    const float* __restrict__ y, unsigned int* __restrict__ ws,
    float* __restrict__ out)
{
    __shared__ unsigned int chunk[256];
    __shared__ unsigned int fine[32];
    __shared__ unsigned long long keys[SELCAP];
    __shared__ float4 sboxes[SELCAP];
    __shared__ int s_coarse;
    __shared__ int s_bstar;
    __shared__ unsigned int s_m;
    __shared__ int s_picks;
    __shared__ unsigned int s_idx[10];
    __shared__ float s_score[10];
    __shared__ float4 s_box[10];
    __shared__ int s_cls[10];

    const int t = threadIdx.x;
    const uint2* bucket = (const uint2*)&ws[WS_BUCKET];

    // ---- per-chunk clamped counts (32 bins per thread, vectorized)
    unsigned int ssum = 0;
    {
        const uint4* cnt4 = (const uint4*)&ws[WS_CNT];
        #pragma unroll
        for (int i = 0; i < 8; i++) {
            uint4 v = cnt4[t * 8 + i];
            ssum += min(v.x, (unsigned int)CAP) + min(v.y, (unsigned int)CAP)
                  + min(v.z, (unsigned int)CAP) + min(v.w, (unsigned int)CAP);
        }
    }
    chunk[t] = ssum;
    for (int i = t; i < SELCAP; i += 256) keys[i] = 0ull;
    if (t == 0) s_m = 0u;
    __syncthreads();

    // ---- parallel suffix sum over the 256 chunks (Hillis-Steele)
    for (int off = 1; off < 256; off <<= 1) {
        unsigned int v = chunk[t];
        unsigned int a = (t + off < 256) ? chunk[t + off] : 0u;
        __syncthreads();
        chunk[t] = v + a;
        __syncthreads();
    }
    const unsigned int total  = chunk[0];
    const unsigned int target = (total < (unsigned int)TOPK) ? total
                                                             : (unsigned int)TOPK;

    if (target > 0) {           // block-uniform branch; barriers inside are legal
        // coarse chunk: largest c with suffix[c] >= target
        if (chunk[t] >= target && (t == 255 || chunk[t + 1] < target))
            s_coarse = t;
        __syncthreads();

        const int cb = s_coarse * 32;
        if (t < 32) fine[t] = min(ws[WS_CNT + cb + t], (unsigned int)CAP);
        __syncthreads();
        for (int off = 1; off < 32; off <<= 1) {
            unsigned int v = 0, a = 0;
            if (t < 32) { v = fine[t]; a = (t + off < 32) ? fine[t + off] : 0u; }
            __syncthreads();
            if (t < 32) fine[t] = v + a;
            __syncthreads();
        }
        const unsigned int base = (s_coarse < 255) ? chunk[s_coarse + 1] : 0u;
        if (t < 32) {
            unsigned int sfx = base + fine[t];
            unsigned int nxt = (t == 31) ? base : base + fine[t + 1];
            if (sfx >= target && nxt < target) s_bstar = cb + t;
        }
    } else {
        if (t == 0) s_bstar = NBINS;
    }
    __syncthreads();

    // ---- gather all entries from bins >= b* (order fixed by the sort below)
    for (int bin = s_bstar + t; bin < NBINS; bin += 256) {
        unsigned int c = ws[WS_CNT + bin];
        if (c > (unsigned int)CAP) c = CAP;
        for (unsigned int j = 0; j < c; j++) {
            uint2 cv = bucket[bin * CAP + j];
            unsigned int pos = atomicAdd(&s_m, 1u);
            if (pos < (unsigned int)SELCAP)
                keys[pos] = ((unsigned long long)cv.x << 32) |
                            (unsigned long long)(0xFFFFFFFFu - cv.y);
        }
    }
    __syncthreads();
    unsigned int M = s_m;
    if (M > (unsigned int)SELCAP) M = SELCAP;

    // ---- bitonic sort, descending: (score desc, idx asc)
    for (int k = 2; k <= SELCAP; k <<= 1) {
        for (int j = k >> 1; j > 0; j >>= 1) {
            for (int i = t; i < SELCAP; i += 256) {
                int ixj = i ^ j;
                if (ixj > i) {
                    unsigned long long a = keys[i], b = keys[ixj];
                    bool descSeg = ((i & k) == 0);
                    if (descSeg ? (a < b) : (a > b)) { keys[i] = b; keys[ixj] = a; }
                }
            }
            __syncthreads();
        }
    }

    // ---- decode boxes for the sorted prefix
    for (int i = t; i < (int)M; i += 256) {
        unsigned int idx = 0xFFFFFFFFu - (unsigned int)(keys[i] & 0xFFFFFFFFull);
        const float* p = y + (size_t)idx * 85;
        float x  = clip01(p[0] / 416.0f);
        float yy = clip01(p[1] / 416.0f);
        float w  = clip01(p[2] / 416.0f);
        float h  = clip01(p[3] / 416.0f);
        sboxes[i] = make_float4(clip01(x - w * 0.5f), clip01(yy - h * 0.5f),
                                clip01(x + w * 0.5f), clip01(yy + h * 0.5f));
    }
    __syncthreads();

    // ---- sequential greedy-NMS scan (exact equivalent of the 10-step argmax loop)
    if (t == 0) {
        int np = 0;
        for (int i = 0; i < (int)M && np < 10; i++) {
            float4 b = sboxes[i];
            bool ok = true;
            for (int kk = 0; kk < np; kk++) {
                float4 r = s_box[kk];
                float ix1 = fmaxf(r.x, b.x);
                float iy1 = fmaxf(r.y, b.y);
                float ix2 = fminf(r.z, b.z);
                float iy2 = fminf(r.w, b.w);
                float inter = fmaxf(ix2 - ix1, 0.0f) * fmaxf(iy2 - iy1, 0.0f);
                float aref = (r.z - r.x) * (r.w - r.y);
                float aall = (b.z - b.x) * (b.w - b.y);
                float iou = inter / (aref + aall - inter + 1e-10f);
                if (iou > 0.45f) { ok = false; break; }
            }
            if (ok) {
                s_box[np] = b;
                s_idx[np] = 0xFFFFFFFFu - (unsigned int)(keys[i] & 0xFFFFFFFFull);
                s_score[np] = __uint_as_float((unsigned int)(keys[i] >> 32));
                np++;
            }
        }
        s_picks = np;
    }
    __syncthreads();

    // ---- class (argmax of 80 probs) for each pick: 16 lanes per pick
    {
        int p = t >> 4, s = t & 15;
        float bv = -1.0f; int bc = 1 << 20;
        if (p < s_picks) {
            const float* pr = y + (size_t)s_idx[p] * 85 + 5;
            #pragma unroll
            for (int kk = 0; kk < 5; kk++) {
                float v = pr[s + 16 * kk];
                int c = s + 16 * kk;
                if (v > bv) { bv = v; bc = c; }
            }
        }
        #pragma unroll
        for (int m = 8; m >= 1; m >>= 1) {
            float ov = __shfl_xor(bv, m, 64);
            int   oc = __shfl_xor(bc, m, 64);
            if (ov > bv || (ov == bv && oc < bc)) { bv = ov; bc = oc; }
        }
        if (p < s_picks && s == 0) s_cls[p] = bc;
    }
    __syncthreads();

    if (t == 0) {
        const float* r0 = (const float*)&ws[WS_ROW0];
        float score0 = r0[0], class0 = r0[1];
        float4 box0 = make_float4(r0[2], r0[3], r0[4], r0[5]);
        for (int kk = 0; kk < 10; kk++) {
            bool v = kk < s_picks;
            float4 b = v ? s_box[kk] : box0;
            out[4 * kk + 0] = b.x;
            out[4 * kk + 1] = b.y;
            out[4 * kk + 2] = b.z;
            out[4 * kk + 3] = b.w;
            out[40 + kk] = v ? s_score[kk] : score0;
            out[50 + kk] = v ? (float)s_cls[kk] : class0;
            out[60 + kk] = v ? 1.0f : 0.0f;
        }
    }
}

extern "C" void kernel_launch(void* const* d_in, const int* in_sizes, int n_in,
                              void* d_out, int out_size, void* d_ws, size_t ws_size,
                              hipStream_t stream)
{
    const float* y = (const float*)d_in[0];
    unsigned int* ws = (unsigned int*)d_ws;

    init_kernel<<<dim3(NBINS / 256), dim3(256), 0, stream>>>(ws);
    decode_kernel<<<dim3(ROWS / 16), dim3(256), 0, stream>>>(y, ws);
    nms_kernel<<<dim3(1), dim3(256), 0, stream>>>(y, ws, (float*)d_out);
}

// Round 7
// 70.398 us; speedup vs baseline: 1.1823x; 1.1092x over previous
//
#include <hip/hip_runtime.h>

#define ROWS   681408        // 64 * 10647
#define NBINS  8192
#define CAP    64            // bucket capacity per bin
#define TOPK   192
#define SELCAP 256

// ws word offsets
#define WS_ROW0     4        // 6 floats: score, class, x1,y1,x2,y2
#define WS_CNT      16       // 8192 uints -> words 16..8207 (16B aligned)
#define WS_BUCKET   8448     // uint2[NBINS*CAP] -> 1,048,576 words (4 MB)

__device__ __forceinline__ float clip01(float v) {
    return fminf(fmaxf(v, 0.0f), 1.0f);
}

__global__ void init_kernel(unsigned int* __restrict__ ws) {
    int i = blockIdx.x * 256 + threadIdx.x;
    if (i < NBINS) ws[WS_CNT + i] = 0u;
}

__global__ __launch_bounds__(256) void decode_kernel(
    const float* __restrict__ y, unsigned int* __restrict__ ws)
{
    const int t    = threadIdx.x;
    const int lane = t & 63;
    const int wave = t >> 6;
    const int s    = lane & 3;        // quad slot 0..3
    const int qr   = lane >> 2;       // row within wave 0..15
    const int row  = blockIdx.x * 64 + wave * 16 + qr;   // exact grid

    const float*  p  = y + (size_t)row * 85;
    // row base byte offset = 340*row, 4-mod-16 in general; gfx9+ global loads
    // tolerate dword alignment (precedent: round-6 float2 at 4-mod-8, bit-exact)
    const float4* p4 = (const float4*)p;

    // lane s owns float4 indices {s, s+4, s+8, s+12, s+16} = elems 4s+16j..+3
    float4 f0 = p4[s];
    float4 f1 = p4[s + 4];
    float4 f2 = p4[s + 8];
    float4 f3 = p4[s + 12];
    float4 f4v = p4[s + 16];
    // tail elems 80..84: lane0 takes 80..83 (float4 #20), lane1 takes 84
    float4 ft = make_float4(-1.0f, -1.0f, -1.0f, -1.0f);
    float e84 = -1.0f;
    if (s == 0) ft = p4[20];
    if (s == 1) e84 = p[84];

    // per-lane argmax over probs (elems 5..84), folding owned elements in
    // ascending order with strict > (first-index-wins = jnp.argmax), then
    // 2-step quad reduce with min-class tie-break.
    float bv = -1.0f; int bc = 1 << 20;
    {
        const int b0 = 4 * s;
        if (b0 + 0 >= 5 && f0.x > bv) { bv = f0.x; bc = b0 - 5; }
        if (b0 + 1 >= 5 && f0.y > bv) { bv = f0.y; bc = b0 - 4; }
        if (b0 + 2 >= 5 && f0.z > bv) { bv = f0.z; bc = b0 - 3; }
        if (b0 + 3 >= 5 && f0.w > bv) { bv = f0.w; bc = b0 - 2; }
        if (f1.x > bv) { bv = f1.x; bc = b0 + 11; }
        if (f1.y > bv) { bv = f1.y; bc = b0 + 12; }
        if (f1.z > bv) { bv = f1.z; bc = b0 + 13; }
        if (f1.w > bv) { bv = f1.w; bc = b0 + 14; }
        if (f2.x > bv) { bv = f2.x; bc = b0 + 27; }
        if (f2.y > bv) { bv = f2.y; bc = b0 + 28; }
        if (f2.z > bv) { bv = f2.z; bc = b0 + 29; }
        if (f2.w > bv) { bv = f2.w; bc = b0 + 30; }
        if (f3.x > bv) { bv = f3.x; bc = b0 + 43; }
        if (f3.y > bv) { bv = f3.y; bc = b0 + 44; }
        if (f3.z > bv) { bv = f3.z; bc = b0 + 45; }
        if (f3.w > bv) { bv = f3.w; bc = b0 + 46; }
        if (f4v.x > bv) { bv = f4v.x; bc = b0 + 59; }
        if (f4v.y > bv) { bv = f4v.y; bc = b0 + 60; }
        if (f4v.z > bv) { bv = f4v.z; bc = b0 + 61; }
        if (f4v.w > bv) { bv = f4v.w; bc = b0 + 62; }
        if (s == 0) {
            if (ft.x > bv) { bv = ft.x; bc = 75; }
            if (ft.y > bv) { bv = ft.y; bc = 76; }
            if (ft.z > bv) { bv = ft.z; bc = 77; }
            if (ft.w > bv) { bv = ft.w; bc = 78; }
        }
        if (s == 1 && e84 > bv) { bv = e84; bc = 79; }
    }

    #pragma unroll
    for (int m = 1; m <= 2; m <<= 1) {
        float ov = __shfl_xor(bv, m, 64);
        int   oc = __shfl_xor(bc, m, 64);
        if (ov > bv || (ov == bv && oc < bc)) { bv = ov; bc = oc; }
    }

    // conf = elem 4 = quad-lane-1's f0.x
    float cf = __shfl(f0.x, (lane & 60) + 1, 64);

    if (s == 0) {
        // box = elems 0..3 = this lane's f0
        float score = cf * bv;
        float x  = clip01(f0.x / 416.0f);
        float yy = clip01(f0.y / 416.0f);
        float w  = clip01(f0.z / 416.0f);
        float h  = clip01(f0.w / 416.0f);
        float x1 = clip01(x  - w * 0.5f);
        float y1 = clip01(yy - h * 0.5f);
        float x2 = clip01(x  + w * 0.5f);
        float y2 = clip01(yy + h * 0.5f);
        bool keep = (((x2 - x1) * (y2 - y1)) > 0.0005f) && (score > 0.5f);
        if (keep) {
            int bin = (int)((score - 0.5f) * (2.0f * (float)NBINS));
            bin = min(max(bin, 0), NBINS - 1);
            unsigned int pos = atomicAdd(&ws[WS_CNT + bin], 1u);
            if (pos < (unsigned int)CAP) {
                uint2* bucket = (uint2*)&ws[WS_BUCKET];
                bucket[bin * CAP + pos] =
                    make_uint2(__float_as_uint(score), (unsigned int)row);
            }
        }
        if (row == 0) {
            float* r0 = (float*)&ws[WS_ROW0];
            r0[0] = score; r0[1] = (float)bc;
            r0[2] = x1; r0[3] = y1; r0[4] = x2; r0[5] = y2;
        }
    }
}

__global__ __launch_bounds__(256) void nms_kernel(
    const float* __restrict__ y, unsigned int* __restrict__ ws,
    float* __restrict__ out)
{
    __shared__ unsigned int chunk[256];
    __shared__ unsigned int fine[32];
    __shared__ unsigned long long keys[SELCAP];
    __shared__ float4 sboxes[SELCAP];
    __shared__ int s_coarse;
    __shared__ int s_bstar;
    __shared__ unsigned int s_m;
    __shared__ int s_picks;
    __shared__ unsigned int s_idx[10];
    __shared__ float s_score[10];
    __shared__ float4 s_box[10];
    __shared__ int s_cls[10];

    const int t = threadIdx.x;
    const uint2* bucket = (const uint2*)&ws[WS_BUCKET];

    // ---- per-chunk clamped counts (32 bins per thread, vectorized)
    unsigned int ssum = 0;
    {
        const uint4* cnt4 = (const uint4*)&ws[WS_CNT];
        #pragma unroll
        for (int i = 0; i < 8; i++) {
            uint4 v = cnt4[t * 8 + i];
            ssum += min(v.x, (unsigned int)CAP) + min(v.y, (unsigned int)CAP)
                  + min(v.z, (unsigned int)CAP) + min(v.w, (unsigned int)CAP);
        }
    }
    chunk[t] = ssum;
    for (int i = t; i < SELCAP; i += 256) keys[i] = 0ull;
    if (t == 0) s_m = 0u;
    __syncthreads();

    // ---- parallel suffix sum over the 256 chunks (Hillis-Steele)
    for (int off = 1; off < 256; off <<= 1) {
        unsigned int v = chunk[t];
        unsigned int a = (t + off < 256) ? chunk[t + off] : 0u;
        __syncthreads();
        chunk[t] = v + a;
        __syncthreads();
    }
    const unsigned int total  = chunk[0];
    const unsigned int target = (total < (unsigned int)TOPK) ? total
                                                             : (unsigned int)TOPK;

    if (target > 0) {           // block-uniform branch; barriers inside are legal
        // coarse chunk: largest c with suffix[c] >= target
        if (chunk[t] >= target && (t == 255 || chunk[t + 1] < target))
            s_coarse = t;
        __syncthreads();

        const int cb = s_coarse * 32;
        if (t < 32) fine[t] = min(ws[WS_CNT + cb + t], (unsigned int)CAP);
        __syncthreads();
        for (int off = 1; off < 32; off <<= 1) {
            unsigned int v = 0, a = 0;
            if (t < 32) { v = fine[t]; a = (t + off < 32) ? fine[t + off] : 0u; }
            __syncthreads();
            if (t < 32) fine[t] = v + a;
            __syncthreads();
        }
        const unsigned int base = (s_coarse < 255) ? chunk[s_coarse + 1] : 0u;
        if (t < 32) {
            unsigned int sfx = base + fine[t];
            unsigned int nxt = (t == 31) ? base : base + fine[t + 1];
            if (sfx >= target && nxt < target) s_bstar = cb + t;
        }
    } else {
        if (t == 0) s_bstar = NBINS;
    }
    __syncthreads();

    // ---- gather all entries from bins >= b* (order fixed by the sort below)
    for (int bin = s_bstar + t; bin < NBINS; bin += 256) {
        unsigned int c = ws[WS_CNT + bin];
        if (c > (unsigned int)CAP) c = CAP;
        for (unsigned int j = 0; j < c; j++) {
            uint2 cv = bucket[bin * CAP + j];
            unsigned int pos = atomicAdd(&s_m, 1u);
            if (pos < (unsigned int)SELCAP)
                keys[pos] = ((unsigned long long)cv.x << 32) |
                            (unsigned long long)(0xFFFFFFFFu - cv.y);
        }
    }
    __syncthreads();
    unsigned int M = s_m;
    if (M > (unsigned int)SELCAP) M = SELCAP;

    // ---- bitonic sort, descending: (score desc, idx asc)
    for (int k = 2; k <= SELCAP; k <<= 1) {
        for (int j = k >> 1; j > 0; j >>= 1) {
            for (int i = t; i < SELCAP; i += 256) {
                int ixj = i ^ j;
                if (ixj > i) {
                    unsigned long long a = keys[i], b = keys[ixj];
                    bool descSeg = ((i & k) == 0);
                    if (descSeg ? (a < b) : (a > b)) { keys[i] = b; keys[ixj] = a; }
                }
            }
            __syncthreads();
        }
    }

    // ---- decode boxes for the sorted prefix
    for (int i = t; i < (int)M; i += 256) {
        unsigned int idx = 0xFFFFFFFFu - (unsigned int)(keys[i] & 0xFFFFFFFFull);
        const float* p = y + (size_t)idx * 85;
        float x  = clip01(p[0] / 416.0f);
        float yy = clip01(p[1] / 416.0f);
        float w  = clip01(p[2] / 416.0f);
        float h  = clip01(p[3] / 416.0f);
        sboxes[i] = make_float4(clip01(x - w * 0.5f), clip01(yy - h * 0.5f),
                                clip01(x + w * 0.5f), clip01(yy + h * 0.5f));
    }
    __syncthreads();

    // ---- sequential greedy-NMS scan (exact equivalent of the 10-step argmax loop)
    if (t == 0) {
        int np = 0;
        for (int i = 0; i < (int)M && np < 10; i++) {
            float4 b = sboxes[i];
            bool ok = true;
            for (int kk = 0; kk < np; kk++) {
                float4 r = s_box[kk];
                float ix1 = fmaxf(r.x, b.x);
                float iy1 = fmaxf(r.y, b.y);
                float ix2 = fminf(r.z, b.z);
                float iy2 = fminf(r.w, b.w);
                float inter = fmaxf(ix2 - ix1, 0.0f) * fmaxf(iy2 - iy1, 0.0f);
                float aref = (r.z - r.x) * (r.w - r.y);
                float aall = (b.z - b.x) * (b.w - b.y);
                float iou = inter / (aref + aall - inter + 1e-10f);
                if (iou > 0.45f) { ok = false; break; }
            }
            if (ok) {
                s_box[np] = b;
                s_idx[np] = 0xFFFFFFFFu - (unsigned int)(keys[i] & 0xFFFFFFFFull);
                s_score[np] = __uint_as_float((unsigned int)(keys[i] >> 32));
                np++;
            }
        }
        s_picks = np;
    }
    __syncthreads();

    // ---- class (argmax of 80 probs) for each pick: 16 lanes per pick
    {
        int p = t >> 4, s = t & 15;
        float bv = -1.0f; int bc = 1 << 20;
        if (p < s_picks) {
            const float* pr = y + (size_t)s_idx[p] * 85 + 5;
            #pragma unroll
            for (int kk = 0; kk < 5; kk++) {
                float v = pr[s + 16 * kk];
                int c = s + 16 * kk;
                if (v > bv) { bv = v; bc = c; }
            }
        }
        #pragma unroll
        for (int m = 8; m >= 1; m >>= 1) {
            float ov = __shfl_xor(bv, m, 64);
            int   oc = __shfl_xor(bc, m, 64);
            if (ov > bv || (ov == bv && oc < bc)) { bv = ov; bc = oc; }
        }
        if (p < s_picks && s == 0) s_cls[p] = bc;
    }
    __syncthreads();

    if (t == 0) {
        const float* r0 = (const float*)&ws[WS_ROW0];
        float score0 = r0[0], class0 = r0[1];
        float4 box0 = make_float4(r0[2], r0[3], r0[4], r0[5]);
        for (int kk = 0; kk < 10; kk++) {
            bool v = kk < s_picks;
            float4 b = v ? s_box[kk] : box0;
            out[4 * kk + 0] = b.x;
            out[4 * kk + 1] = b.y;
            out[4 * kk + 2] = b.z;
            out[4 * kk + 3] = b.w;
            out[40 + kk] = v ? s_score[kk] : score0;
            out[50 + kk] = v ? (float)s_cls[kk] : class0;
            out[60 + kk] = v ? 1.0f : 0.0f;
        }
    }
}

extern "C" void kernel_launch(void* const* d_in, const int* in_sizes, int n_in,
                              void* d_out, int out_size, void* d_ws, size_t ws_size,
                              hipStream_t stream)
{
    const float* y = (const float*)d_in[0];
    unsigned int* ws = (unsigned int*)d_ws;

    init_kernel<<<dim3(NBINS / 256), dim3(256), 0, stream>>>(ws);
    decode_kernel<<<dim3(ROWS / 64), dim3(256), 0, stream>>>(y, ws);
    nms_kernel<<<dim3(1), dim3(256), 0, stream>>>(y, ws, (float*)d_out);
}